// Round 5
// baseline (282.361 us; speedup 1.0000x reference)
//
#include <hip/hip_runtime.h>
#include <math.h>

// Problem constants
#define Bsz 64
#define IC  512   // in_caps
#define KD  128   // in_dim
#define NC  32    // num_caps
#define DC  32    // dim_caps
#define CHUNK 64  // in_caps per block (ACX phase)
#define NCH   8   // IC / CHUNK
#define GBLK  512 // 2 blocks/CU on 256 CUs — co-resident for sw barrier
#define NTHR  256

#define CSTR 36   // padded stride for c_sT / wv_sT rows
#define BSTR 68   // padded stride for bb_s rows
#define WSTR 33   // padded stride for w_s rows

// workspace layout (floats)
#define CXP_SZ (Bsz * NCH * NC * KD)   // 8 MB   cx partials [b][ch][n][k]
#define WV_SZ  (Bsz * NC * KD)         // 1 MB   wv [b][n][k]
#define BB_SZ  (Bsz * NC * IC)         // 4 MB   bb after iter-1 update

// x_s: row i holds k-quads rotated by (i>>2)
__device__ __forceinline__ int xaddr(int i, int kq) {
    return i * KD + ((((kq) + (i >> 2)) & 31) << 2);
}

// Software grid barrier.
// Arrive: fetch_add RELEASE (one buffer_wbl2 — publishes this XCD's dirty L2).
// Spin:   RELAXED loads (no cache maintenance per iteration!  R4's ACQUIRE spin
//         emitted a buffer_inv every iteration -> invalidate storm, 220 us).
// Exit:   one ACQUIRE load (one buffer_inv — discards stale L2 lines).
__device__ __forceinline__ void gridbar(unsigned* c, unsigned target) {
    __syncthreads();   // drains vmcnt: all waves' stores are in L2 before release
    if (threadIdx.x == 0) {
        __hip_atomic_fetch_add(c, 1u, __ATOMIC_RELEASE, __HIP_MEMORY_SCOPE_AGENT);
        unsigned tries = 0;
        while (__hip_atomic_load(c, __ATOMIC_RELAXED, __HIP_MEMORY_SCOPE_AGENT) < target &&
               tries < (1u << 22)) {
            ++tries;
            __builtin_amdgcn_s_sleep(8);
        }
        (void)__hip_atomic_load(c, __ATOMIC_ACQUIRE, __HIP_MEMORY_SCOPE_AGENT);
    }
    __syncthreads();
}

__global__ __launch_bounds__(NTHR, 2)
void capsAll(const float* __restrict__ x_g, const float* __restrict__ W_g,
             const float* __restrict__ b0_g, float* __restrict__ out_g,
             float* __restrict__ cxp, float* __restrict__ wv_g,
             float* __restrict__ bb_ws, unsigned* __restrict__ ctr)
{
    __shared__ float x_s[CHUNK * KD];      // 32 KB (phase B aliases: cxs, vs_s)
    __shared__ float bb_s[NC * BSTR];      // 8.5 KB
    __shared__ float scr[KD * CSTR];       // 18 KB: wv_sT / c_sT / w_s

    const int t = threadIdx.x, blk = blockIdx.x;
    // ACX mapping: block owns (batch b, chunk ch)
    const int b = blk >> 3, ch = blk & 7, i0g = ch * CHUNK;
    // B mapping: block owns capsule pb_n for 4 batches at pb_b0
    const int pb_n = blk & 31, pb_b0 = (blk >> 5) * 4;

    float* cxs  = x_s;            // [4][128]  (phase B)
    float* vs_s = x_s + 512;      // [4][32]   (phase B)
    float* w_s  = scr;            // [128][33] (phase B)

    int slot = 0;
    for (int r = 0; r < 3; ++r) {
        const float* bb_in = (r <= 1) ? b0_g : bb_ws;
        const int do_uv = (r > 0), write_bb = (r == 1), final_ = (r == 2);

        __syncthreads();   // protect x_s/scr reuse from previous B phase

        // ---------- ACX: [uv + bb update] + softmax + cx partials ----------
        for (int rep = 0; rep < 8; ++rep) {
            int v = t + rep * NTHR;            // float4 idx 0..2047
            int i = v >> 5, kq = v & 31;
            *(float4*)(x_s + xaddr(i, kq)) =
                *(const float4*)(x_g + ((size_t)(b * IC + i0g + i)) * KD + (kq << 2));
        }
        for (int rep = 0; rep < 2; ++rep) {
            int v = t + rep * NTHR;            // 0..511
            int n = v >> 4, i4 = v & 15;
            *(float4*)(bb_s + n * BSTR + (i4 << 2)) =
                *(const float4*)(bb_in + ((size_t)(b * NC + n)) * IC + i0g + (i4 << 2));
        }
        if (do_uv) {
            for (int rep = 0; rep < 4; ++rep) {
                const int n = t & 31;
                const int k4 = (t >> 5) + (rep << 3);   // 0..31
                float4 v4 = *(const float4*)(wv_g + ((size_t)(b * NC) + n) * KD + (k4 << 2));
                scr[(k4 * 4 + 0) * CSTR + n] = v4.x;
                scr[(k4 * 4 + 1) * CSTR + n] = v4.y;
                scr[(k4 * 4 + 2) * CSTR + n] = v4.z;
                scr[(k4 * 4 + 3) * CSTR + n] = v4.w;
            }
        }
        __syncthreads();

        if (do_uv) {
            if (t < 128) {
                const int tn = t & 7, ti = t >> 3;
                const int n0 = tn << 2, i0 = ti << 2;
                float4 a0 = {0,0,0,0}, a1 = {0,0,0,0}, a2 = {0,0,0,0}, a3 = {0,0,0,0};
                for (int kq = 0; kq < 32; ++kq) {
                    const float4 xr0 = *(const float4*)(x_s + xaddr(i0 + 0, kq));
                    const float4 xr1 = *(const float4*)(x_s + xaddr(i0 + 1, kq));
                    const float4 xr2 = *(const float4*)(x_s + xaddr(i0 + 2, kq));
                    const float4 xr3 = *(const float4*)(x_s + xaddr(i0 + 3, kq));
                    const float4 w0 = *(const float4*)(scr + (kq * 4 + 0) * CSTR + n0);
                    const float4 w1 = *(const float4*)(scr + (kq * 4 + 1) * CSTR + n0);
                    const float4 w2 = *(const float4*)(scr + (kq * 4 + 2) * CSTR + n0);
                    const float4 w3 = *(const float4*)(scr + (kq * 4 + 3) * CSTR + n0);
                    a0.x += xr0.x*w0.x + xr0.y*w1.x + xr0.z*w2.x + xr0.w*w3.x;
                    a0.y += xr0.x*w0.y + xr0.y*w1.y + xr0.z*w2.y + xr0.w*w3.y;
                    a0.z += xr0.x*w0.z + xr0.y*w1.z + xr0.z*w2.z + xr0.w*w3.z;
                    a0.w += xr0.x*w0.w + xr0.y*w1.w + xr0.z*w2.w + xr0.w*w3.w;
                    a1.x += xr1.x*w0.x + xr1.y*w1.x + xr1.z*w2.x + xr1.w*w3.x;
                    a1.y += xr1.x*w0.y + xr1.y*w1.y + xr1.z*w2.y + xr1.w*w3.y;
                    a1.z += xr1.x*w0.z + xr1.y*w1.z + xr1.z*w2.z + xr1.w*w3.z;
                    a1.w += xr1.x*w0.w + xr1.y*w1.w + xr1.z*w2.w + xr1.w*w3.w;
                    a2.x += xr2.x*w0.x + xr2.y*w1.x + xr2.z*w2.x + xr2.w*w3.x;
                    a2.y += xr2.x*w0.y + xr2.y*w1.y + xr2.z*w2.y + xr2.w*w3.y;
                    a2.z += xr2.x*w0.z + xr2.y*w1.z + xr2.z*w2.z + xr2.w*w3.z;
                    a2.w += xr2.x*w0.w + xr2.y*w1.w + xr2.z*w2.w + xr2.w*w3.w;
                    a3.x += xr3.x*w0.x + xr3.y*w1.x + xr3.z*w2.x + xr3.w*w3.x;
                    a3.y += xr3.x*w0.y + xr3.y*w1.y + xr3.z*w2.y + xr3.w*w3.y;
                    a3.z += xr3.x*w0.z + xr3.y*w1.z + xr3.z*w2.z + xr3.w*w3.z;
                    a3.w += xr3.x*w0.w + xr3.y*w1.w + xr3.z*w2.w + xr3.w*w3.w;
                }
                bb_s[(n0+0)*BSTR + i0+0] += a0.x; bb_s[(n0+1)*BSTR + i0+0] += a0.y;
                bb_s[(n0+2)*BSTR + i0+0] += a0.z; bb_s[(n0+3)*BSTR + i0+0] += a0.w;
                bb_s[(n0+0)*BSTR + i0+1] += a1.x; bb_s[(n0+1)*BSTR + i0+1] += a1.y;
                bb_s[(n0+2)*BSTR + i0+1] += a1.z; bb_s[(n0+3)*BSTR + i0+1] += a1.w;
                bb_s[(n0+0)*BSTR + i0+2] += a2.x; bb_s[(n0+1)*BSTR + i0+2] += a2.y;
                bb_s[(n0+2)*BSTR + i0+2] += a2.z; bb_s[(n0+3)*BSTR + i0+2] += a2.w;
                bb_s[(n0+0)*BSTR + i0+3] += a3.x; bb_s[(n0+1)*BSTR + i0+3] += a3.y;
                bb_s[(n0+2)*BSTR + i0+3] += a3.z; bb_s[(n0+3)*BSTR + i0+3] += a3.w;
            }
            __syncthreads();
            if (write_bb) {
                for (int rep = 0; rep < 2; ++rep) {
                    int v = t + rep * NTHR;
                    int n = v >> 4, i4 = v & 15;
                    *(float4*)(bb_ws + ((size_t)(b * NC + n)) * IC + i0g + (i4 << 2)) =
                        *(const float4*)(bb_s + n * BSTR + (i4 << 2));
                }
            }
        }

        // softmax over n; write c^T into scr
        if (t < CHUNK) {
            const int ii = t;
            float m = -1e30f;
            #pragma unroll
            for (int n = 0; n < NC; ++n) m = fmaxf(m, bb_s[n * BSTR + ii]);
            float e[NC]; float sum = 0.f;
            #pragma unroll
            for (int n = 0; n < NC; ++n) { float ev = __expf(bb_s[n * BSTR + ii] - m); e[n] = ev; sum += ev; }
            const float inv = 1.f / sum;
            float* crow = scr + ii * CSTR;
            #pragma unroll
            for (int n = 0; n < NC; ++n) crow[n] = e[n] * inv;
        }
        __syncthreads();

        // cx = C @ X; each thread 4n x 4k
        {
            const int tn = t & 7, tk = t >> 3;
            const int n0 = tn << 2;
            float4 acc0 = {0,0,0,0}, acc1 = {0,0,0,0}, acc2 = {0,0,0,0}, acc3 = {0,0,0,0};
            for (int ii = 0; ii < CHUNK; ++ii) {
                const float4 c4 = *(const float4*)(scr + ii * CSTR + n0);
                const float4 x4 = *(const float4*)(x_s + xaddr(ii, tk));
                acc0.x += c4.x*x4.x; acc0.y += c4.x*x4.y; acc0.z += c4.x*x4.z; acc0.w += c4.x*x4.w;
                acc1.x += c4.y*x4.x; acc1.y += c4.y*x4.y; acc1.z += c4.y*x4.z; acc1.w += c4.y*x4.w;
                acc2.x += c4.z*x4.x; acc2.y += c4.z*x4.y; acc2.z += c4.z*x4.z; acc2.w += c4.z*x4.w;
                acc3.x += c4.w*x4.x; acc3.y += c4.w*x4.y; acc3.z += c4.w*x4.z; acc3.w += c4.w*x4.w;
            }
            float* base = cxp + ((size_t)(b * NCH + ch)) * NC * KD + (tk << 2);
            *(float4*)(base + (size_t)(n0 + 0) * KD) = acc0;
            *(float4*)(base + (size_t)(n0 + 1) * KD) = acc1;
            *(float4*)(base + (size_t)(n0 + 2) * KD) = acc2;
            *(float4*)(base + (size_t)(n0 + 3) * KD) = acc3;
        }

        gridbar(ctr + slot, GBLK); ++slot;   // cx partials visible

        // ---------- phase B: reduce partials, s = cx@W, squash, wv/out ----------
        for (int rep = 0; rep < 4; ++rep) {
            int v = t + rep * NTHR;            // 0..1023
            int k = v >> 3, d0 = (v & 7) << 2;
            float4 w4 = *(const float4*)(W_g + (size_t)pb_n * KD * DC + (v << 2));
            float* dst = w_s + k * WSTR + d0;
            dst[0] = w4.x; dst[1] = w4.y; dst[2] = w4.z; dst[3] = w4.w;
        }
        if (t < 128) {
            const int bsub = t >> 5, k4 = t & 31;
            float4 s4 = {0,0,0,0};
            const float* p = cxp + (((size_t)(pb_b0 + bsub) * NCH) * NC + pb_n) * KD + (k4 << 2);
            #pragma unroll
            for (int c2 = 0; c2 < NCH; ++c2) {
                float4 v4 = *(const float4*)(p + (size_t)c2 * NC * KD);
                s4.x += v4.x; s4.y += v4.y; s4.z += v4.z; s4.w += v4.w;
            }
            *(float4*)(cxs + bsub * KD + (k4 << 2)) = s4;
        }
        __syncthreads();

        if (t < 128) {
            const int bsub = t >> 5, d = t & 31;
            float s = 0.f;
            const float* crow = cxs + bsub * KD;
            for (int k = 0; k < KD; ++k) s += crow[k] * w_s[k * WSTR + d];
            float sn = s * s;
            #pragma unroll
            for (int off = 1; off < 32; off <<= 1) sn += __shfl_xor(sn, off, 64);
            const float vv = s * (sn / ((1.f + sn) * (sqrtf(sn) + 1e-8f)));
            if (final_) {
                out_g[((size_t)(pb_b0 + bsub) * NC + pb_n) * DC + d] = vv;
            } else {
                vs_s[bsub * DC + d] = vv;
            }
        }
        if (!final_) {
            __syncthreads();
            // wv[k] = W[k,:].v ; thread = (bg 0..1, k 0..127), 2 b's each
            const int k = t & 127, bg = t >> 7;
            #pragma unroll
            for (int q = 0; q < 2; ++q) {
                const int bs = bg * 2 + q;
                float a = 0.f;
                #pragma unroll
                for (int dd = 0; dd < DC; ++dd) a += w_s[k * WSTR + dd] * vs_s[bs * DC + dd];
                wv_g[((size_t)(pb_b0 + bs) * NC + pb_n) * KD + k] = a;
            }
            gridbar(ctr + slot, GBLK); ++slot;   // wv visible
        }
    }
}

extern "C" void kernel_launch(void* const* d_in, const int* in_sizes, int n_in,
                              void* d_out, int out_size, void* d_ws, size_t ws_size,
                              hipStream_t stream) {
    const float* x  = (const float*)d_in[0];
    const float* W  = (const float*)d_in[1];
    const float* b0 = (const float*)d_in[2];
    float* out = (float*)d_out;

    float* cxp   = (float*)d_ws;                 // 8 MB
    float* wv    = cxp + CXP_SZ;                 // 1 MB
    float* bb_ws = wv + WV_SZ;                   // 4 MB
    unsigned* ctr = (unsigned*)(bb_ws + BB_SZ);  // 8 barrier slots

    hipMemsetAsync(ctr, 0, 8 * sizeof(unsigned), stream);
    capsAll<<<GBLK, NTHR, 0, stream>>>(x, W, b0, out, cxp, wv, bb_ws, ctr);
}

// Round 6
// 199.465 us; speedup vs baseline: 1.4156x; 1.4156x over previous
//
#include <hip/hip_runtime.h>
#include <math.h>

// Problem constants
#define IC 512    // in_caps
#define KD 128    // in_dim
#define NC 32     // num_caps
#define DC 32     // dim_caps
#define NTHR 512
#define SSTR 132  // s_s row stride (f32): bank rotation 4 per row, 16B-aligned
#define WVSTR 36  // wv_T row stride (f32): bank rotation 4 per row, 16B-aligned

// One block per batch element. No grid barriers, no workspace, one launch.
// LDS: c_s 32KB (c or uv staging, half of i at a time) + u_s 18KB (s | wv_T) + v_s 4KB.
__global__ __launch_bounds__(NTHR, 1)
void caps64(const float* __restrict__ x_g, const float* __restrict__ W_g,
            const float* __restrict__ b0_g, float* __restrict__ out_g)
{
    __shared__ float c_s[256 * NC];     // 32 KB: c rows (per half) / uv staging / reduce scratch
    __shared__ float u_s[KD * WVSTR];   // 18 KB union: s_s[32][SSTR] | wv_T[128][WVSTR]
    __shared__ float v_s[NC * 33];      // 4.2 KB

    const int t = threadIdx.x, b = blockIdx.x;
    const float* __restrict__ xb = x_g + (size_t)b * IC * KD;

    // routing logits for row i = t live in registers
    float bb[NC];
    #pragma unroll
    for (int n = 0; n < NC; ++n)
        bb[n] = b0_g[((size_t)(b * NC + n)) * IC + t];

    // cx mapping: lanes = k_grp(4b) | i_lo(2b); waves = n_grp(2b) | i_hi(1b)
    const int ckg = t & 15, cil = (t >> 4) & 3, cng = (t >> 6) & 3, cih = t >> 8;
    const int cig = cih * 4 + cil;              // i_grp 0..7 (32 rows each, within a 256-half)
    const int ck0 = ckg << 3, cn0 = cng << 3;   // 8k x 8n register tile
    // uv mapping: 2 rows x 8 n per thread
    const int un0 = (t & 3) << 3, uig = t >> 2;
    // sW / wv mapping
    const int sn_ = t >> 4, sdp = t & 15;
    const int myhalf = t >> 8, myrow = t & 255;

    for (int r = 0; r < 3; ++r) {
        if (r > 0) {
            // ---------- uv: bb[i][n] += sum_k x[i][k] * wv[n][k]  (wv_T in u_s) ----------
            for (int h = 0; h < 2; ++h) {
                float acc0[8], acc1[8];
                #pragma unroll
                for (int nn = 0; nn < 8; ++nn) { acc0[nn] = 0.f; acc1[nn] = 0.f; }
                const float* xr = xb + (size_t)(h * 256 + uig * 2) * KD;
                for (int kq = 0; kq < 32; ++kq) {
                    float4 x0 = *(const float4*)(xr + (kq << 2));
                    float4 x1 = *(const float4*)(xr + KD + (kq << 2));
                    const float xa[4] = {x0.x, x0.y, x0.z, x0.w};
                    const float xc[4] = {x1.x, x1.y, x1.z, x1.w};
                    #pragma unroll
                    for (int j = 0; j < 4; ++j) {
                        const float* wr = u_s + ((kq << 2) + j) * WVSTR + un0;
                        float4 w0 = *(const float4*)(wr);
                        float4 w1 = *(const float4*)(wr + 4);
                        const float wv8[8] = {w0.x,w0.y,w0.z,w0.w,w1.x,w1.y,w1.z,w1.w};
                        #pragma unroll
                        for (int nn = 0; nn < 8; ++nn) {
                            acc0[nn] += xa[j] * wv8[nn];
                            acc1[nn] += xc[j] * wv8[nn];
                        }
                    }
                }
                {   // stage uv tiles into c_s (free: all prior readers sync'd)
                    float4 s00 = {acc0[0],acc0[1],acc0[2],acc0[3]};
                    float4 s01 = {acc0[4],acc0[5],acc0[6],acc0[7]};
                    float4 s10 = {acc1[0],acc1[1],acc1[2],acc1[3]};
                    float4 s11 = {acc1[4],acc1[5],acc1[6],acc1[7]};
                    float* d0 = c_s + (uig * 2) * NC + un0;
                    *(float4*)(d0) = s00;       *(float4*)(d0 + 4) = s01;
                    *(float4*)(d0 + NC) = s10;  *(float4*)(d0 + NC + 4) = s11;
                }
                __syncthreads();
                if (myhalf == h) {              // row owner folds uv into bb
                    const float* rsrc = c_s + myrow * NC;
                    #pragma unroll
                    for (int q = 0; q < 8; ++q) {
                        float4 u4 = *(const float4*)(rsrc + (q << 2));
                        bb[(q<<2)+0] += u4.x; bb[(q<<2)+1] += u4.y;
                        bb[(q<<2)+2] += u4.z; bb[(q<<2)+3] += u4.w;
                    }
                }
                __syncthreads();
            }
        }

        // ---------- softmax (in-register, per row) + cx accumulate, by i-halves ----------
        float cacc[8][8];
        #pragma unroll
        for (int nn = 0; nn < 8; ++nn)
            #pragma unroll
            for (int kk = 0; kk < 8; ++kk) cacc[nn][kk] = 0.f;

        for (int h = 0; h < 2; ++h) {
            if (myhalf == h) {
                float m = bb[0];
                #pragma unroll
                for (int n = 1; n < NC; ++n) m = fmaxf(m, bb[n]);
                float e[NC]; float sum = 0.f;
                #pragma unroll
                for (int n = 0; n < NC; ++n) { e[n] = __expf(bb[n] - m); sum += e[n]; }
                const float inv = 1.f / sum;
                float* dst = c_s + myrow * NC;
                #pragma unroll
                for (int q = 0; q < 8; ++q) {
                    float4 c4 = {e[(q<<2)]*inv, e[(q<<2)+1]*inv, e[(q<<2)+2]*inv, e[(q<<2)+3]*inv};
                    *(float4*)(dst + (q << 2)) = c4;
                }
            }
            __syncthreads();
            const float* xh = xb + (size_t)(h * 256) * KD;
            #pragma unroll 2
            for (int ii = 0; ii < 32; ++ii) {
                const int i = cig * 32 + ii;
                const float* crow = c_s + i * NC + cn0;
                const float* xrow = xh + (size_t)i * KD + ck0;
                float4 c0 = *(const float4*)(crow);
                float4 c1 = *(const float4*)(crow + 4);
                float4 y0 = *(const float4*)(xrow);
                float4 y1 = *(const float4*)(xrow + 4);
                const float cv[8] = {c0.x,c0.y,c0.z,c0.w,c1.x,c1.y,c1.z,c1.w};
                const float xv[8] = {y0.x,y0.y,y0.z,y0.w,y1.x,y1.y,y1.z,y1.w};
                #pragma unroll
                for (int nn = 0; nn < 8; ++nn)
                    #pragma unroll
                    for (int kk = 0; kk < 8; ++kk)
                        cacc[nn][kk] += cv[nn] * xv[kk];
            }
            __syncthreads();
        }

        // reduce cacc over i_lo (lane bits 4,5) in-wave, then across i_hi via LDS
        #pragma unroll
        for (int nn = 0; nn < 8; ++nn)
            #pragma unroll
            for (int kk = 0; kk < 8; ++kk) {
                float vsum = cacc[nn][kk];
                vsum += __shfl_xor(vsum, 16);
                vsum += __shfl_xor(vsum, 32);
                cacc[nn][kk] = vsum;
            }
        if (cih == 1 && cil == 0) {
            #pragma unroll
            for (int nn = 0; nn < 8; ++nn) {
                float4 p0 = {cacc[nn][0],cacc[nn][1],cacc[nn][2],cacc[nn][3]};
                float4 p1 = {cacc[nn][4],cacc[nn][5],cacc[nn][6],cacc[nn][7]};
                float* d = c_s + (cn0 + nn) * KD + ck0;
                *(float4*)(d) = p0; *(float4*)(d + 4) = p1;
            }
        }
        __syncthreads();
        if (cih == 0 && cil == 0) {
            #pragma unroll
            for (int nn = 0; nn < 8; ++nn) {
                const float* p = c_s + (cn0 + nn) * KD + ck0;
                float4 q0 = *(const float4*)(p);
                float4 q1 = *(const float4*)(p + 4);
                float4 f0 = {cacc[nn][0]+q0.x, cacc[nn][1]+q0.y, cacc[nn][2]+q0.z, cacc[nn][3]+q0.w};
                float4 f1 = {cacc[nn][4]+q1.x, cacc[nn][5]+q1.y, cacc[nn][6]+q1.z, cacc[nn][7]+q1.w};
                float* d = u_s + (cn0 + nn) * SSTR + ck0;
                *(float4*)(d) = f0; *(float4*)(d + 4) = f1;
            }
        }
        __syncthreads();

        // ---------- s @ W[n] + squash; thread (n, d-pair) ----------
        float s0 = 0.f, s1 = 0.f;
        const float* srow = u_s + sn_ * SSTR;
        const float* wrow = W_g + (size_t)sn_ * KD * DC + (sdp << 1);
        #pragma unroll 8
        for (int k = 0; k < KD; ++k) {
            const float sv = srow[k];
            s0 += sv * wrow[k * DC];
            s1 += sv * wrow[k * DC + 1];
        }
        float sq = s0 * s0 + s1 * s1;
        sq += __shfl_xor(sq, 1); sq += __shfl_xor(sq, 2);
        sq += __shfl_xor(sq, 4); sq += __shfl_xor(sq, 8);
        const float fac = sq / ((1.f + sq) * (sqrtf(sq) + 1e-8f));
        const float v0 = s0 * fac, v1 = s1 * fac;
        if (r == 2) {
            float* o = out_g + ((size_t)(b * NC + sn_)) * DC + (sdp << 1);
            o[0] = v0; o[1] = v1;
        } else {
            v_s[sn_ * 33 + (sdp << 1)] = v0;
            v_s[sn_ * 33 + (sdp << 1) + 1] = v1;
            __syncthreads();   // v ready; s_s dead -> u_s reusable as wv_T
            float vv[DC];
            {
                const float* vrow = v_s + sn_ * 33;
                #pragma unroll
                for (int d = 0; d < DC; ++d) vv[d] = vrow[d];
            }
            const float* Wn = W_g + (size_t)sn_ * KD * DC;
            #pragma unroll
            for (int j = 0; j < 8; ++j) {
                const int k = sdp + (j << 4);
                const float* wr2 = Wn + k * DC;
                float a = 0.f;
                #pragma unroll
                for (int d = 0; d < DC; ++d) a += wr2[d] * vv[d];
                u_s[k * WVSTR + sn_] = a;   // wv_T[k][n]
            }
            __syncthreads();   // wv_T ready for next iteration's uv
        }
    }
}

extern "C" void kernel_launch(void* const* d_in, const int* in_sizes, int n_in,
                              void* d_out, int out_size, void* d_ws, size_t ws_size,
                              hipStream_t stream) {
    const float* x  = (const float*)d_in[0];
    const float* W  = (const float*)d_in[1];
    const float* b0 = (const float*)d_in[2];
    float* out = (float*)d_out;
    caps64<<<64, NTHR, 0, stream>>>(x, W, b0, out);
}

// Round 7
// 156.320 us; speedup vs baseline: 1.8063x; 1.2760x over previous
//
#include <hip/hip_runtime.h>
#include <math.h>

#define IC 512
#define KD 128
#define NC 32
#define DC 32
#define NTHR 512

typedef __attribute__((ext_vector_type(8))) short bf16x8;
typedef __attribute__((ext_vector_type(4))) float f32x4;

__device__ __forceinline__ unsigned short f2bf(float f) {
    unsigned u = __builtin_bit_cast(unsigned, f);
    return (unsigned short)((u + 0x7fffu + ((u >> 16) & 1u)) >> 16);
}
__device__ __forceinline__ float bf2f(unsigned short h) {
    unsigned u = ((unsigned)h) << 16;
    return __builtin_bit_cast(float, u);
}
#define MFMA(a, b, c) __builtin_amdgcn_mfma_f32_16x16x32_bf16(a, b, c, 0, 0, 0)

// LDS regions:
//  uA   : 512*34 ushort = 34816 B  — union: uv stage [512][34] / c_bf [32][520] / f32 tile [64][133]
//  s_s  : 32*128 float  = 16384 B  — s[n][k], within-row rotation (k + 4n)&31
//  wv_s : 32*136 ushort =  8704 B  — wv bf16 [n][k], row pad 136 (272 B, 16B-aligned, banks n*4)
__global__ __launch_bounds__(NTHR, 1)
void capsmfma(const float* __restrict__ x_g, const float* __restrict__ W_g,
              const float* __restrict__ b0_g, float* __restrict__ out_g,
              unsigned short* __restrict__ xT_g)
{
    __shared__ __align__(16) unsigned short uA[512 * 34];
    __shared__ __align__(16) float s_s[NC * KD];
    __shared__ __align__(16) unsigned short wv_s[NC * 136];

    const int t = threadIdx.x, b = blockIdx.x;
    const int w = t >> 6, l = t & 63;
    const float* __restrict__ xb = x_g + (size_t)b * IC * KD;
    unsigned short* __restrict__ xTb = xT_g + (size_t)b * KD * IC;

    // ---------------- prologue: x (f32 row-major) -> xT_bf[k][i] in workspace ----------------
    {
        float* tile = (float*)uA;             // [64][133]
        for (int c = 0; c < 8; ++c) {
            for (int rep = 0; rep < 4; ++rep) {
                int v = t + rep * NTHR;       // f4 idx 0..2047
                int i = v >> 5, kq = v & 31;
                float4 val = *(const float4*)(xb + (size_t)(c * 64 + i) * KD + (kq << 2));
                float* d = tile + i * 133 + (kq << 2);
                d[0] = val.x; d[1] = val.y; d[2] = val.z; d[3] = val.w;
            }
            __syncthreads();
            {
                const int xk = t >> 2, iseg = t & 3;
                unsigned q[8];
                #pragma unroll
                for (int j = 0; j < 8; ++j) {
                    unsigned short lo = f2bf(tile[(iseg * 16 + 2 * j) * 133 + xk]);
                    unsigned short hi = f2bf(tile[(iseg * 16 + 2 * j + 1) * 133 + xk]);
                    q[j] = (unsigned)lo | ((unsigned)hi << 16);
                }
                unsigned short* dst = xTb + (size_t)xk * IC + c * 64 + iseg * 16;
                float4 o0 = {__builtin_bit_cast(float, q[0]), __builtin_bit_cast(float, q[1]),
                             __builtin_bit_cast(float, q[2]), __builtin_bit_cast(float, q[3])};
                float4 o1 = {__builtin_bit_cast(float, q[4]), __builtin_bit_cast(float, q[5]),
                             __builtin_bit_cast(float, q[6]), __builtin_bit_cast(float, q[7])};
                *(float4*)(dst) = o0;
                *(float4*)(dst + 8) = o1;
            }
            __syncthreads();
        }
    }

    // routing logits for row i = t, in registers
    float bb[NC];
    #pragma unroll
    for (int n = 0; n < NC; ++n)
        bb[n] = b0_g[((size_t)(b * NC + n)) * IC + t];

    unsigned short* stage = uA;   // [512][34]
    unsigned short* c_bf  = uA;   // [32][520]

    for (int r = 0; r < 3; ++r) {
        if (r > 0) {
            // ---- phase U: uv[i][n] = sum_k x[i][k]*wv[n][k]; MFMA M=i,N=n,K=k ----
            // wave w owns i in [64w, 64w+64): mtiles 4w..4w+3; ntiles 0..1; ktiles 0..3
            f32x4 acc[4][2];
            #pragma unroll
            for (int m4 = 0; m4 < 4; ++m4)
                #pragma unroll
                for (int nt = 0; nt < 2; ++nt) acc[m4][nt] = (f32x4){0.f, 0.f, 0.f, 0.f};
            const int lm = l & 15, kg = l >> 4;
            for (int kt = 0; kt < 4; ++kt) {
                const int xk = kt * 32 + kg * 8;
                bf16x8 bfr0 = *(const bf16x8*)(const void*)(wv_s + (0 * 16 + lm) * 136 + xk);
                bf16x8 bfr1 = *(const bf16x8*)(const void*)(wv_s + (1 * 16 + lm) * 136 + xk);
                #pragma unroll
                for (int m4 = 0; m4 < 4; ++m4) {
                    const int i = (4 * w + m4) * 16 + lm;
                    float4 xa = *(const float4*)(xb + (size_t)i * KD + xk);
                    float4 xc = *(const float4*)(xb + (size_t)i * KD + xk + 4);
                    bf16x8 afr;
                    afr[0] = (short)f2bf(xa.x); afr[1] = (short)f2bf(xa.y);
                    afr[2] = (short)f2bf(xa.z); afr[3] = (short)f2bf(xa.w);
                    afr[4] = (short)f2bf(xc.x); afr[5] = (short)f2bf(xc.y);
                    afr[6] = (short)f2bf(xc.z); afr[7] = (short)f2bf(xc.w);
                    acc[m4][0] = MFMA(afr, bfr0, acc[m4][0]);
                    acc[m4][1] = MFMA(afr, bfr1, acc[m4][1]);
                }
            }
            // stage D: uv[i = (4w+m4)*16 + (l>>4)*4+reg][n = nt*16 + (l&15)]
            #pragma unroll
            for (int m4 = 0; m4 < 4; ++m4)
                #pragma unroll
                for (int nt = 0; nt < 2; ++nt)
                    #pragma unroll
                    for (int reg = 0; reg < 4; ++reg) {
                        const int i = (4 * w + m4) * 16 + kg * 4 + reg;
                        const int n = nt * 16 + lm;
                        stage[i * 34 + n] = f2bf(acc[m4][nt][reg]);
                    }
            __syncthreads();
            #pragma unroll
            for (int n = 0; n < NC; ++n) bb[n] += bf2f(stage[t * 34 + n]);
            __syncthreads();
        }

        // ---- softmax over n (registers, owner thread t = row i) -> c_bf[n][i] ----
        {
            float m = bb[0];
            #pragma unroll
            for (int n = 1; n < NC; ++n) m = fmaxf(m, bb[n]);
            float e[NC], sum = 0.f;
            #pragma unroll
            for (int n = 0; n < NC; ++n) { e[n] = __expf(bb[n] - m); sum += e[n]; }
            const float inv = 1.f / sum;
            #pragma unroll
            for (int n = 0; n < NC; ++n) c_bf[n * 520 + t] = f2bf(e[n] * inv);
        }
        __syncthreads();

        // ---- phase C: s[n][xk] = sum_i c[n][i]*x[i][xk]; MFMA M=n,N=xk,K=i ----
        // wave w owns xk-tile w; mtiles 0..1; ktiles 0..15
        {
            f32x4 acc2[2];
            acc2[0] = (f32x4){0.f, 0.f, 0.f, 0.f};
            acc2[1] = (f32x4){0.f, 0.f, 0.f, 0.f};
            const int lm = l & 15, kg = l >> 4;
            for (int kt = 0; kt < 16; ++kt) {
                const int i0 = kt * 32 + kg * 8;
                float4 raw = *(const float4*)(xTb + (size_t)(w * 16 + lm) * IC + i0);
                bf16x8 bfr = __builtin_bit_cast(bf16x8, raw);
                #pragma unroll
                for (int mt = 0; mt < 2; ++mt) {
                    bf16x8 afr = *(const bf16x8*)(const void*)(c_bf + (mt * 16 + lm) * 520 + i0);
                    acc2[mt] = MFMA(afr, bfr, acc2[mt]);
                }
            }
            #pragma unroll
            for (int mt = 0; mt < 2; ++mt)
                #pragma unroll
                for (int reg = 0; reg < 4; ++reg) {
                    const int n = mt * 16 + kg * 4 + reg;
                    const int xk = w * 16 + lm;
                    s_s[n * KD + (xk & 96) + ((xk + 4 * n) & 31)] = acc2[mt][reg];
                }
        }
        __syncthreads();

        // ---- phase W: s@W[n] + squash; thread (n = t>>4, dp = t&15) ----
        {
            const int n = t >> 4, dp = t & 15;
            const float* __restrict__ Wn = W_g + (size_t)n * KD * DC;
            float s0 = 0.f, s1 = 0.f;
            #pragma unroll 8
            for (int k = 0; k < KD; ++k) {
                const float sv = s_s[n * KD + (k & 96) + ((k + 4 * n) & 31)];
                const float2 wp = *(const float2*)(Wn + k * DC + (dp << 1));
                s0 += sv * wp.x; s1 += sv * wp.y;
            }
            float sn = s0 * s0 + s1 * s1;
            sn += __shfl_xor(sn, 1); sn += __shfl_xor(sn, 2);
            sn += __shfl_xor(sn, 4); sn += __shfl_xor(sn, 8);
            const float fac = sn / ((1.f + sn) * (sqrtf(sn) + 1e-8f));
            const float v0 = s0 * fac, v1 = s1 * fac;
            if (r == 2) {
                float* o = out_g + ((size_t)(b * NC + n)) * DC + (dp << 1);
                o[0] = v0; o[1] = v1;
            } else {
                // gather v[0..31] of this n from the 16-lane group, compute wv[n][k]
                float vv[DC];
                const int base = (l >> 4) << 4;
                #pragma unroll
                for (int dd = 0; dd < 16; ++dd) {
                    vv[2 * dd]     = __shfl(v0, base + dd);
                    vv[2 * dd + 1] = __shfl(v1, base + dd);
                }
                #pragma unroll
                for (int kk = 0; kk < 8; ++kk) {
                    const int k = dp * 8 + kk;
                    const float* __restrict__ wr = Wn + k * DC;
                    float a = 0.f;
                    #pragma unroll
                    for (int dd = 0; dd < DC; ++dd) a += wr[dd] * vv[dd];
                    wv_s[n * 136 + k] = f2bf(a);
                }
                __syncthreads();   // wv ready for next r's phase U
            }
        }
    }
}

extern "C" void kernel_launch(void* const* d_in, const int* in_sizes, int n_in,
                              void* d_out, int out_size, void* d_ws, size_t ws_size,
                              hipStream_t stream) {
    const float* x  = (const float*)d_in[0];
    const float* W  = (const float*)d_in[1];
    const float* b0 = (const float*)d_in[2];
    float* out = (float*)d_out;
    unsigned short* xT = (unsigned short*)d_ws;   // 8 MB bf16 x-transpose
    capsmfma<<<64, NTHR, 0, stream>>>(x, W, b0, out, xT);
}